// Round 11
// baseline (597.330 us; speedup 1.0000x reference)
//
#include <hip/hip_runtime.h>
#include <hip/hip_fp16.h>

#define N_NODES 100000
#define N_EDGES 3200000
#define N_GRAPHS 64
#define HID 128
#define NBUCK 782            // ceil(100000/128) buckets of 128 dst-nodes
#define NPART 256            // partition blocks
#define EPB (N_EDGES / NPART)  // 12500 edges per partition block (exact)

typedef _Float16 half8 __attribute__((ext_vector_type(8)));
typedef float floatx4 __attribute__((ext_vector_type(4)));
typedef float floatx2 __attribute__((ext_vector_type(2)));

__device__ inline unsigned char f32_to_fp8(float v) {
    int p = __builtin_amdgcn_cvt_pk_fp8_f32(v, v, 0, false);
    return (unsigned char)(p & 0xff);
}

// ================= CSR build: LDS-staged counting sort (no device atomics) =========
__global__ __launch_bounds__(256) void hist_kernel(const int* __restrict__ dst,
                                                   int* __restrict__ hist_g) {
    __shared__ int lh[NBUCK];
    int t = threadIdx.x, b = blockIdx.x;
    for (int j = t; j < NBUCK; j += 256) lh[j] = 0;
    __syncthreads();
    int beg = b * EPB, end = beg + EPB;
    for (int i = beg + t; i < end; i += 256) atomicAdd(&lh[dst[i] >> 7], 1);
    __syncthreads();
    for (int j = t; j < NBUCK; j += 256) hist_g[j * NPART + b] = lh[j];
}

// bucket totals: one wave per bucket, lane holds one int4 (256 vals = 64 lanes x 4)
__global__ __launch_bounds__(256) void tot_kernel(const int* __restrict__ hist_g,
                                                  int* __restrict__ tot) {
    int wave = blockIdx.x * 4 + (threadIdx.x >> 6);
    if (wave >= NBUCK) return;
    int lane = threadIdx.x & 63;
    const int4* h4 = (const int4*)(hist_g + (size_t)wave * NPART);
    int4 v = h4[lane];
    int s = v.x + v.y + v.z + v.w;
    #pragma unroll
    for (int off = 32; off > 0; off >>= 1) s += __shfl_down(s, off, 64);
    if (lane == 0) tot[wave] = s;
}

// exclusive scan of 782 bucket totals -> bucket bases bb[], row_ptr[N]
__global__ __launch_bounds__(1024) void scan_tot(const int* __restrict__ tot,
                                                 int* __restrict__ bb,
                                                 int* __restrict__ row_ptrN) {
    __shared__ int buf[1024];
    int t = threadIdx.x;
    int v = (t < NBUCK) ? tot[t] : 0;
    buf[t] = v;
    __syncthreads();
    for (int off = 1; off < 1024; off <<= 1) {
        int x = (t >= off) ? buf[t - off] : 0;
        __syncthreads();
        buf[t] += x;
        __syncthreads();
    }
    if (t < NBUCK) bb[t] = buf[t] - v;
    if (t == NBUCK - 1) {
        bb[NBUCK] = buf[t];
        row_ptrN[0] = buf[t];
    }
}

// rewrite hist to per-(bucket,block) running global offsets: one wave per bucket
__global__ __launch_bounds__(256) void offs_kernel(int* __restrict__ hist_g,
                                                   const int* __restrict__ bb) {
    int wave = blockIdx.x * 4 + (threadIdx.x >> 6);
    if (wave >= NBUCK) return;
    int lane = threadIdx.x & 63;
    int4* h4 = (int4*)(hist_g + (size_t)wave * NPART);
    int4 v = h4[lane];
    int s = v.x + v.y + v.z + v.w;
    int e = s;
    #pragma unroll
    for (int off = 1; off < 64; off <<= 1) {
        int x = __shfl_up(e, off, 64);
        if (lane >= off) e += x;
    }
    e -= s;  // exclusive within wave
    int base = bb[wave] + e;
    int4 o;
    o.x = base; base += v.x;
    o.y = base; base += v.y;
    o.z = base; base += v.z;
    o.w = base;
    h4[lane] = o;
}

// partition edges into bucket-contiguous ebuf; pack (src | (dst&127)<<17) in one int
// (src < 2^17; halves ebuf traffic vs int2)
__global__ __launch_bounds__(256) void part_kernel(const int* __restrict__ src,
                                                   const int* __restrict__ dst,
                                                   const int* __restrict__ hist_g,
                                                   int* __restrict__ ebuf) {
    __shared__ int lf[NBUCK];
    int t = threadIdx.x, b = blockIdx.x;
    for (int j = t; j < NBUCK; j += 256) lf[j] = hist_g[j * NPART + b];
    __syncthreads();
    int beg = b * EPB, end = beg + EPB;
    for (int i = beg + t; i < end; i += 256) {
        int s = src[i], d = dst[i];
        int pos = atomicAdd(&lf[d >> 7], 1);
        ebuf[pos] = s | ((d & 127) << 17);
    }
}

__global__ __launch_bounds__(256) void build_kernel(const int* __restrict__ ebuf,
                                                    const int* __restrict__ bb,
                                                    int* __restrict__ row_ptr,
                                                    int* __restrict__ col,
                                                    float* __restrict__ dis, int n) {
    __shared__ int c[128], fl[128], sc[128];
    int t = threadIdx.x, k = blockIdx.x;
    if (t < 128) c[t] = 0;
    __syncthreads();
    int beg = bb[k], end = bb[k + 1];
    for (int i = beg + t; i < end; i += 256) atomicAdd(&c[(ebuf[i] >> 17) & 127], 1);
    __syncthreads();
    if (t < 128) sc[t] = c[t];
    __syncthreads();
    for (int off = 1; off < 128; off <<= 1) {
        int x = (t >= off && t < 128) ? sc[t - off] : 0;
        __syncthreads();
        if (t < 128) sc[t] += x;
        __syncthreads();
    }
    if (t < 128) {
        int rb = beg + sc[t] - c[t];
        fl[t] = rb;
        int node = k * 128 + t;
        if (node < n) {
            row_ptr[node] = rb;
            dis[node] = rsqrtf((float)c[t] + 1.0f);
        }
    }
    __syncthreads();
    for (int i = beg + t; i < end; i += 256) {
        int e = ebuf[i];
        int pos = atomicAdd(&fl[(e >> 17) & 127], 1);
        col[pos] = e & 0x1FFFF;
    }
}

// ---------------- per-node prep: g1 = dis * x (fp16) ----------------
__global__ void prep_kernel(const float* __restrict__ x, const float* __restrict__ dis,
                            __half* __restrict__ g1, int n) {
    int i = blockIdx.x * blockDim.x + threadIdx.x;
    if (i < n) {
        float ds = dis[i];
        const float4* xr = (const float4*)(x + (size_t)i * 8);
        float4 x0 = xr[0], x1 = xr[1];
        __half2 h0 = __floats2half2_rn(ds * x0.x, ds * x0.y);
        __half2 h1 = __floats2half2_rn(ds * x0.z, ds * x0.w);
        __half2 h2 = __floats2half2_rn(ds * x1.x, ds * x1.y);
        __half2 h3 = __floats2half2_rn(ds * x1.z, ds * x1.w);
        uint2 v0, v1;
        v0.x = *(unsigned*)&h0; v0.y = *(unsigned*)&h1;
        v1.x = *(unsigned*)&h2; v1.y = *(unsigned*)&h3;
        uint2* o = (uint2*)(g1 + (size_t)i * 8);
        o[0] = v0; o[1] = v1;
    }
}

// ---------------- layer-1 pre-aggregation on 8-dim input ----------------
__global__ __launch_bounds__(256) void agg1_kernel(const __half* __restrict__ g1,
                                                   const int* __restrict__ row_ptr,
                                                   const int* __restrict__ col,
                                                   const float* __restrict__ dis,
                                                   float* __restrict__ p, int n) {
    int node = blockIdx.x * 4 + (threadIdx.x >> 6);
    if (node >= n) return;
    int lane = threadIdx.x & 63;
    int grp = lane >> 2;   // edge slot 0..15
    int fid = lane & 3;    // feature pair id
    int beg = row_ptr[node], end = row_ptr[node + 1];
    float a0 = 0.f, a1 = 0.f;
    for (int e0 = beg; e0 < end; e0 += 16) {
        int m = end - e0;
        if (grp < m) {
            int c = __builtin_nontemporal_load(&col[e0 + grp]);
            __half2 h2 = *(const __half2*)(g1 + (size_t)c * 8 + fid * 2);
            float2 f = __half22float2(h2);
            a0 += f.x; a1 += f.y;
        }
    }
    a0 += __shfl_xor(a0, 4);  a1 += __shfl_xor(a1, 4);
    a0 += __shfl_xor(a0, 8);  a1 += __shfl_xor(a1, 8);
    a0 += __shfl_xor(a0, 16); a1 += __shfl_xor(a1, 16);
    a0 += __shfl_xor(a0, 32); a1 += __shfl_xor(a1, 32);
    if (lane < 4) {
        __half2 own = *(const __half2*)(g1 + (size_t)node * 8 + fid * 2);
        float2 fo = __half22float2(own);
        float d = dis[node];
        *(float2*)(p + (size_t)node * 8 + fid * 2) = make_float2(d * (a0 + fo.x), d * (a1 + fo.y));
    }
}

__device__ inline uint2 f4_to_h4(float4 v) {
    __half2 a = __floats2half2_rn(v.x, v.y);
    __half2 b = __floats2half2_rn(v.z, v.w);
    uint2 r;
    r.x = *(unsigned*)&a;
    r.y = *(unsigned*)&b;
    return r;
}

// ---------------- GEMM layer 1: p[N x 8] fp32 @ W[8 x 128] + b, relu -> fp16 -------
__global__ __launch_bounds__(256) void gemm_k8(const float* __restrict__ A,
                                               const float* __restrict__ W,
                                               const float* __restrict__ bias,
                                               __half* __restrict__ out, int n) {
    __shared__ float4 Ws[8 * 32];
    const float4* W4 = (const float4*)W;
    for (int i = threadIdx.x; i < 8 * 32; i += 256) Ws[i] = W4[i];
    __syncthreads();
    int r = blockIdx.x * 256 + threadIdx.x;
    if (r >= n) return;
    float4 acc[32];
    #pragma unroll
    for (int j = 0; j < 32; j++) acc[j] = make_float4(0.f, 0.f, 0.f, 0.f);
    const float4* Arow = (const float4*)(A + (size_t)r * 8);
    float4 a0 = Arow[0], a1 = Arow[1];
    float av[8] = {a0.x, a0.y, a0.z, a0.w, a1.x, a1.y, a1.z, a1.w};
    #pragma unroll
    for (int kk = 0; kk < 8; kk++) {
        float a = av[kk];
        #pragma unroll
        for (int j = 0; j < 32; j++) {
            float4 w = Ws[kk * 32 + j];
            acc[j].x += a * w.x;
            acc[j].y += a * w.y;
            acc[j].z += a * w.z;
            acc[j].w += a * w.w;
        }
    }
    uint2* o = (uint2*)(out + (size_t)r * HID);
    const float4* b4 = (const float4*)bias;
    #pragma unroll
    for (int j = 0; j < 32; j++) {
        float4 b = b4[j];
        float4 v = make_float4(fmaxf(acc[j].x + b.x, 0.f), fmaxf(acc[j].y + b.y, 0.f),
                               fmaxf(acc[j].z + b.z, 0.f), fmaxf(acc[j].w + b.w, 0.f));
        o[j] = f4_to_h4(v);
    }
}

// ---------------- W transpose+convert: Wt[j][k] = (fp16) W[k][j] ----------------
__global__ __launch_bounds__(128) void wconv(const float* __restrict__ W,
                                             __half* __restrict__ Wt) {
    int j = blockIdx.x, k = threadIdx.x;
    Wt[j * 128 + k] = __float2half(W[k * 128 + j]);
}

// ---------------- MFMA GEMM layers 2..5: gq = fp8(dis * (h @ W)) ----------------
__global__ __launch_bounds__(256) void gemm_mfma(const __half* __restrict__ A,
                                                 const __half* __restrict__ Wt,
                                                 const float* __restrict__ dis,
                                                 unsigned char* __restrict__ outq, int n) {
    __shared__ uint4 wt_lds[128 * 17];  // 17 uint4 = 136 halves per row
    __shared__ uint4 a_lds[64 * 17];
    int t = threadIdx.x;
    const uint4* Wg = (const uint4*)Wt;
    #pragma unroll
    for (int i = 0; i < 8; i++) {
        int idx = i * 256 + t;
        int j = idx >> 4, kq = idx & 15;
        wt_lds[j * 17 + kq] = Wg[idx];
    }
    int base = blockIdx.x * 64;
    const uint4* Ag = (const uint4*)A;
    #pragma unroll
    for (int i = 0; i < 4; i++) {
        int idx = i * 256 + t;
        int r = idx >> 4, kq = idx & 15;
        int row = base + r;
        if (row >= n) row = n - 1;
        a_lds[r * 17 + kq] = Ag[(size_t)row * 16 + kq];
    }
    __syncthreads();
    int w = t >> 6, lane = t & 63;
    int m = lane & 15, quad = lane >> 4;
    floatx4 acc[8];
    #pragma unroll
    for (int jt = 0; jt < 8; jt++) acc[jt] = (floatx4)(0.f);
    #pragma unroll
    for (int kc = 0; kc < 4; kc++) {
        uint4 araw = a_lds[(w * 16 + m) * 17 + kc * 4 + quad];
        half8 af = *(half8*)&araw;
        #pragma unroll
        for (int jt = 0; jt < 8; jt++) {
            uint4 braw = wt_lds[(jt * 16 + m) * 17 + kc * 4 + quad];
            half8 bf = *(half8*)&braw;
            acc[jt] = __builtin_amdgcn_mfma_f32_16x16x32_f16(af, bf, acc[jt], 0, 0, 0);
        }
    }
    #pragma unroll
    for (int reg = 0; reg < 4; reg++) {
        int row = base + w * 16 + quad * 4 + reg;
        if (row < n) {
            float ds = dis[row];
            #pragma unroll
            for (int jt = 0; jt < 8; jt++) {
                outq[(size_t)row * 128 + jt * 16 + m] = f32_to_fp8(acc[jt][reg] * ds);
            }
        }
    }
}

// ---------------- aggregation: h_next = relu(dis_d*(sum gq_src + gq_d) + b) ---------
// wave per node; 8 lanes x uint4 (16B fp8) per edge row -> 8 edges per gather instr.
// col is streamed once: nontemporal load keeps gq resident in L2.
__global__ __launch_bounds__(256) void agg_kernel(const unsigned char* __restrict__ gq,
                                                  const int* __restrict__ row_ptr,
                                                  const int* __restrict__ col,
                                                  const float* __restrict__ dis,
                                                  const float* __restrict__ bias,
                                                  __half* __restrict__ out, int n) {
    int node = blockIdx.x * 4 + (threadIdx.x >> 6);
    if (node >= n) return;
    int lane = threadIdx.x & 63;
    int es = lane >> 3;          // edge slot within an 8-edge step
    int fid = lane & 7;          // 16-feature chunk id
    size_t fo = (size_t)fid * 16;
    int beg = row_ptr[node], end = row_ptr[node + 1];
    floatx2 a[8];
    #pragma unroll
    for (int k = 0; k < 8; k++) a[k] = (floatx2){0.f, 0.f};
    for (int e0 = beg; e0 < end; e0 += 64) {
        int m = min(64, end - e0);
        int cl = (lane < m) ? __builtin_nontemporal_load(&col[e0 + lane]) : 0;
        int full = m >> 3;       // complete 8-edge steps (mask-free)
        int j = 0;
        for (; j + 4 <= full; j += 4) {   // 32 edges per unrolled iter, 4 gathers in flight
            int c[4];
            #pragma unroll
            for (int u = 0; u < 4; u++) c[u] = __shfl(cl, (j + u) * 8 + es);
            uint4 raw[4];
            #pragma unroll
            for (int u = 0; u < 4; u++)
                raw[u] = *(const uint4*)(gq + (size_t)c[u] * 128 + fo);
            #pragma unroll
            for (int u = 0; u < 4; u++) {
                unsigned rw[4] = {raw[u].x, raw[u].y, raw[u].z, raw[u].w};
                #pragma unroll
                for (int h = 0; h < 4; h++) {
                    a[h * 2] += __builtin_amdgcn_cvt_pk_f32_fp8(rw[h], false);
                    a[h * 2 + 1] += __builtin_amdgcn_cvt_pk_f32_fp8(rw[h], true);
                }
            }
        }
        for (; j < full; j++) {
            int c = __shfl(cl, j * 8 + es);
            uint4 raw = *(const uint4*)(gq + (size_t)c * 128 + fo);
            unsigned rw[4] = {raw.x, raw.y, raw.z, raw.w};
            #pragma unroll
            for (int h = 0; h < 4; h++) {
                a[h * 2] += __builtin_amdgcn_cvt_pk_f32_fp8(rw[h], false);
                a[h * 2 + 1] += __builtin_amdgcn_cvt_pk_f32_fp8(rw[h], true);
            }
        }
        int rem0 = full * 8;
        if (rem0 < m) {          // one masked pass covers the <8 leftover edges
            int idx = rem0 + es;
            int c = __shfl(cl, idx & 63);
            float val = (idx < m) ? 1.f : 0.f;
            uint4 raw = *(const uint4*)(gq + (size_t)c * 128 + fo);
            unsigned rw[4] = {raw.x, raw.y, raw.z, raw.w};
            #pragma unroll
            for (int h = 0; h < 4; h++) {
                a[h * 2] += val * __builtin_amdgcn_cvt_pk_f32_fp8(rw[h], false);
                a[h * 2 + 1] += val * __builtin_amdgcn_cvt_pk_f32_fp8(rw[h], true);
            }
        }
    }
    float av[16];
    #pragma unroll
    for (int k = 0; k < 8; k++) { av[2 * k] = a[k][0]; av[2 * k + 1] = a[k][1]; }
    #pragma unroll
    for (int k = 0; k < 16; k++) {
        av[k] += __shfl_xor(av[k], 8);
        av[k] += __shfl_xor(av[k], 16);
        av[k] += __shfl_xor(av[k], 32);
    }
    if (lane < 8) {
        float d = dis[node];
        uint4 own = *(const uint4*)(gq + (size_t)node * 128 + fo);
        unsigned ow[4] = {own.x, own.y, own.z, own.w};
        float sv[16];
        #pragma unroll
        for (int h = 0; h < 4; h++) {
            floatx2 lo = __builtin_amdgcn_cvt_pk_f32_fp8(ow[h], false);
            floatx2 hi = __builtin_amdgcn_cvt_pk_f32_fp8(ow[h], true);
            sv[4 * h] = lo[0]; sv[4 * h + 1] = lo[1];
            sv[4 * h + 2] = hi[0]; sv[4 * h + 3] = hi[1];
        }
        float bv[16];
        #pragma unroll
        for (int q4 = 0; q4 < 4; q4++) {
            float4 b = *(const float4*)(bias + fid * 16 + q4 * 4);
            bv[4 * q4] = b.x; bv[4 * q4 + 1] = b.y; bv[4 * q4 + 2] = b.z; bv[4 * q4 + 3] = b.w;
        }
        float o[16];
        #pragma unroll
        for (int k = 0; k < 16; k++) o[k] = fmaxf(d * (av[k] + sv[k]) + bv[k], 0.f);
        uint4 q0, q1;
        __half2 p0 = __floats2half2_rn(o[0], o[1]);
        __half2 p1 = __floats2half2_rn(o[2], o[3]);
        __half2 p2 = __floats2half2_rn(o[4], o[5]);
        __half2 p3 = __floats2half2_rn(o[6], o[7]);
        __half2 p4 = __floats2half2_rn(o[8], o[9]);
        __half2 p5 = __floats2half2_rn(o[10], o[11]);
        __half2 p6 = __floats2half2_rn(o[12], o[13]);
        __half2 p7 = __floats2half2_rn(o[14], o[15]);
        q0.x = *(unsigned*)&p0; q0.y = *(unsigned*)&p1;
        q0.z = *(unsigned*)&p2; q0.w = *(unsigned*)&p3;
        q1.x = *(unsigned*)&p4; q1.y = *(unsigned*)&p5;
        q1.z = *(unsigned*)&p6; q1.w = *(unsigned*)&p7;
        uint4* op = (uint4*)(out + (size_t)node * HID + fid * 16);
        op[0] = q0;
        op[1] = q1;
    }
}

// ---------------- graph boundaries via binary search (batch is sorted) ---------
__global__ __launch_bounds__(128) void gbounds_kernel(const int* __restrict__ batch,
                                                      int* __restrict__ bnd,
                                                      int* __restrict__ gcnt) {
    int g = threadIdx.x;
    if (g <= N_GRAPHS) {
        int lo = 0, hi = N_NODES;
        while (lo < hi) {
            int mid = (lo + hi) >> 1;
            if (batch[mid] < g) lo = mid + 1;
            else hi = mid;
        }
        bnd[g] = lo;
    }
    __syncthreads();
    if (g < N_GRAPHS) gcnt[g] = bnd[g + 1] - bnd[g];
}

__global__ __launch_bounds__(128) void pool_kernel(const __half* __restrict__ h,
                                                   const int* __restrict__ batch,
                                                   float* __restrict__ pooled, int n) {
    int f = threadIdx.x;
    int n0 = blockIdx.x * 64;
    if (n0 >= n) return;
    int n1 = min(n0 + 64, n);
    float acc = 0.f;
    int cur = batch[n0];
    for (int i = n0; i < n1; i++) {
        int b = batch[i];
        if (b != cur) {
            atomicAdd(&pooled[cur * HID + f], acc);
            acc = 0.f;
            cur = b;
        }
        acc += __half2float(h[(size_t)i * HID + f]);
    }
    atomicAdd(&pooled[cur * HID + f], acc);
}

// ---------------- head: mean, dense 128->10, log_softmax ----------------
__global__ __launch_bounds__(128) void final_kernel(const float* __restrict__ pooled,
                                                    const int* __restrict__ gcnt,
                                                    const float* __restrict__ Wout,
                                                    const float* __restrict__ bout,
                                                    float* __restrict__ out) {
    __shared__ float p[HID];
    __shared__ float lg[10];
    __shared__ float lsum;
    int g = blockIdx.x, t = threadIdx.x;
    float c = fmaxf((float)gcnt[g], 1.0f);
    p[t] = pooled[g * HID + t] / c;
    __syncthreads();
    if (t < 10) {
        float s = bout[t];
        for (int f = 0; f < HID; f++) s += p[f] * Wout[f * 10 + t];
        lg[t] = s;
    }
    __syncthreads();
    if (t == 0) {
        float m = lg[0];
        for (int ci = 1; ci < 10; ci++) m = fmaxf(m, lg[ci]);
        float se = 0.f;
        for (int ci = 0; ci < 10; ci++) se += expf(lg[ci] - m);
        lsum = m + logf(se);
    }
    __syncthreads();
    if (t < 10) out[g * 10 + t] = lg[t] - lsum;
}

extern "C" void kernel_launch(void* const* d_in, const int* in_sizes, int n_in,
                              void* d_out, int out_size, void* d_ws, size_t ws_size,
                              hipStream_t stream) {
    const float* x = (const float*)d_in[0];
    const int* ei = (const int*)d_in[1];
    const int* batch = (const int*)d_in[2];
    const float* W[5] = {(const float*)d_in[3], (const float*)d_in[5], (const float*)d_in[7],
                         (const float*)d_in[9], (const float*)d_in[11]};
    const float* B[5] = {(const float*)d_in[4], (const float*)d_in[6], (const float*)d_in[8],
                         (const float*)d_in[10], (const float*)d_in[12]};
    const float* Wout = (const float*)d_in[13];
    const float* bout = (const float*)d_in[14];
    float* out = (float*)d_out;

    const int* src = ei;
    const int* dst = ei + N_EDGES;

    char* ws = (char*)d_ws;
    size_t off = 0;
    auto alloc = [&](size_t bytes) -> char* {
        char* p = ws + off;
        off = (off + bytes + 255) & ~(size_t)255;
        return p;
    };
    float* pooled = (float*)alloc(N_GRAPHS * HID * 4);
    size_t zero_span = off;  // pooled gets memset to 0
    int* gcnt = (int*)alloc(N_GRAPHS * 4);
    int* bnd = (int*)alloc((N_GRAPHS + 1) * 4);
    int* row_ptr = (int*)alloc((N_NODES + 1) * 4);
    float* dis = (float*)alloc(N_NODES * 4);
    int* hist_g = (int*)alloc((size_t)NBUCK * NPART * 4);
    int* tot = (int*)alloc(NBUCK * 4);
    int* bb = (int*)alloc((NBUCK + 1) * 4);
    int* ebuf = (int*)alloc((size_t)N_EDGES * 4);
    int* col = (int*)alloc((size_t)N_EDGES * 4);
    __half* wt = (__half*)alloc(4 * 128 * 128 * 2);
    __half* g1 = (__half*)alloc((size_t)N_NODES * 8 * 2);
    float* p1 = (float*)alloc((size_t)N_NODES * 8 * 4);
    __half* h_a = (__half*)alloc((size_t)N_NODES * HID * 2);
    unsigned char* gq = (unsigned char*)alloc((size_t)N_NODES * HID);

    hipMemsetAsync(d_ws, 0, zero_span, stream);

    int nb = (N_NODES + 255) / 256;
    int wb = (NBUCK + 3) / 4;  // 196 blocks, 4 waves each

    // CSR build: counting sort, zero device-scope atomics, parallel scan
    hist_kernel<<<NPART, 256, 0, stream>>>(dst, hist_g);
    tot_kernel<<<wb, 256, 0, stream>>>(hist_g, tot);
    scan_tot<<<1, 1024, 0, stream>>>(tot, bb, row_ptr + N_NODES);
    offs_kernel<<<wb, 256, 0, stream>>>(hist_g, bb);
    part_kernel<<<NPART, 256, 0, stream>>>(src, dst, hist_g, ebuf);
    build_kernel<<<NBUCK, 256, 0, stream>>>(ebuf, bb, row_ptr, col, dis, N_NODES);

    prep_kernel<<<nb, 256, 0, stream>>>(x, dis, g1, N_NODES);
    gbounds_kernel<<<1, 128, 0, stream>>>(batch, bnd, gcnt);
    for (int l = 1; l < 5; l++)
        wconv<<<128, 128, 0, stream>>>(W[l], wt + (size_t)(l - 1) * 128 * 128);

    int gb = (N_NODES + 255) / 256;
    int ab = (N_NODES + 3) / 4;
    int mb = (N_NODES + 63) / 64;

    // layer 1: agg on 8-dim input, then GEMM 8->128 (+bias, relu)
    agg1_kernel<<<ab, 256, 0, stream>>>(g1, row_ptr, col, dis, p1, N_NODES);
    gemm_k8<<<gb, 256, 0, stream>>>(p1, W[0], B[0], h_a, N_NODES);
    // layers 2..5: MFMA GEMM (gq = fp8(dis*hW)) then agg (+bias, relu)
    for (int l = 1; l < 5; l++) {
        gemm_mfma<<<mb, 256, 0, stream>>>(h_a, wt + (size_t)(l - 1) * 128 * 128, dis, gq,
                                          N_NODES);
        agg_kernel<<<ab, 256, 0, stream>>>(gq, row_ptr, col, dis, B[l], h_a, N_NODES);
    }

    pool_kernel<<<(N_NODES + 63) / 64, 128, 0, stream>>>(h_a, batch, pooled, N_NODES);
    final_kernel<<<N_GRAPHS, 128, 0, stream>>>(pooled, gcnt, Wout, bout, out);
}

// Round 12
// 550.568 us; speedup vs baseline: 1.0849x; 1.0849x over previous
//
#include <hip/hip_runtime.h>
#include <hip/hip_fp16.h>

#define N_NODES 100000
#define N_EDGES 3200000
#define N_GRAPHS 64
#define HID 128
#define NBUCK 782            // ceil(100000/128) buckets of 128 dst-nodes
#define NPART 256            // partition blocks
#define EPB (N_EDGES / NPART)  // 12500 edges per partition block (exact)

typedef _Float16 half8 __attribute__((ext_vector_type(8)));
typedef float floatx4 __attribute__((ext_vector_type(4)));
typedef float floatx2 __attribute__((ext_vector_type(2)));

__device__ inline unsigned char f32_to_fp8(float v) {
    int p = __builtin_amdgcn_cvt_pk_fp8_f32(v, v, 0, false);
    return (unsigned char)(p & 0xff);
}

// ================= CSR build: LDS-staged counting sort (no device atomics) =========
__global__ __launch_bounds__(256) void hist_kernel(const int* __restrict__ dst,
                                                   int* __restrict__ hist_g) {
    __shared__ int lh[NBUCK];
    int t = threadIdx.x, b = blockIdx.x;
    for (int j = t; j < NBUCK; j += 256) lh[j] = 0;
    __syncthreads();
    int beg = b * EPB, end = beg + EPB;
    for (int i = beg + t; i < end; i += 256) atomicAdd(&lh[dst[i] >> 7], 1);
    __syncthreads();
    for (int j = t; j < NBUCK; j += 256) hist_g[j * NPART + b] = lh[j];
}

// bucket totals: one wave per bucket, lane holds one int4 (256 vals = 64 lanes x 4)
__global__ __launch_bounds__(256) void tot_kernel(const int* __restrict__ hist_g,
                                                  int* __restrict__ tot) {
    int wave = blockIdx.x * 4 + (threadIdx.x >> 6);
    if (wave >= NBUCK) return;
    int lane = threadIdx.x & 63;
    const int4* h4 = (const int4*)(hist_g + (size_t)wave * NPART);
    int4 v = h4[lane];
    int s = v.x + v.y + v.z + v.w;
    #pragma unroll
    for (int off = 32; off > 0; off >>= 1) s += __shfl_down(s, off, 64);
    if (lane == 0) tot[wave] = s;
}

// exclusive scan of 782 bucket totals -> bucket bases bb[], row_ptr[N]
__global__ __launch_bounds__(1024) void scan_tot(const int* __restrict__ tot,
                                                 int* __restrict__ bb,
                                                 int* __restrict__ row_ptrN) {
    __shared__ int buf[1024];
    int t = threadIdx.x;
    int v = (t < NBUCK) ? tot[t] : 0;
    buf[t] = v;
    __syncthreads();
    for (int off = 1; off < 1024; off <<= 1) {
        int x = (t >= off) ? buf[t - off] : 0;
        __syncthreads();
        buf[t] += x;
        __syncthreads();
    }
    if (t < NBUCK) bb[t] = buf[t] - v;
    if (t == NBUCK - 1) {
        bb[NBUCK] = buf[t];
        row_ptrN[0] = buf[t];
    }
}

// rewrite hist to per-(bucket,block) running global offsets: one wave per bucket
__global__ __launch_bounds__(256) void offs_kernel(int* __restrict__ hist_g,
                                                   const int* __restrict__ bb) {
    int wave = blockIdx.x * 4 + (threadIdx.x >> 6);
    if (wave >= NBUCK) return;
    int lane = threadIdx.x & 63;
    int4* h4 = (int4*)(hist_g + (size_t)wave * NPART);
    int4 v = h4[lane];
    int s = v.x + v.y + v.z + v.w;
    int e = s;
    #pragma unroll
    for (int off = 1; off < 64; off <<= 1) {
        int x = __shfl_up(e, off, 64);
        if (lane >= off) e += x;
    }
    e -= s;  // exclusive within wave
    int base = bb[wave] + e;
    int4 o;
    o.x = base; base += v.x;
    o.y = base; base += v.y;
    o.z = base; base += v.z;
    o.w = base;
    h4[lane] = o;
}

// partition edges into bucket-contiguous ebuf; pack (src | (dst&127)<<17) in one int
// (src < 2^17; halves ebuf traffic vs int2)
__global__ __launch_bounds__(256) void part_kernel(const int* __restrict__ src,
                                                   const int* __restrict__ dst,
                                                   const int* __restrict__ hist_g,
                                                   int* __restrict__ ebuf) {
    __shared__ int lf[NBUCK];
    int t = threadIdx.x, b = blockIdx.x;
    for (int j = t; j < NBUCK; j += 256) lf[j] = hist_g[j * NPART + b];
    __syncthreads();
    int beg = b * EPB, end = beg + EPB;
    for (int i = beg + t; i < end; i += 256) {
        int s = src[i], d = dst[i];
        int pos = atomicAdd(&lf[d >> 7], 1);
        ebuf[pos] = s | ((d & 127) << 17);
    }
}

__global__ __launch_bounds__(256) void build_kernel(const int* __restrict__ ebuf,
                                                    const int* __restrict__ bb,
                                                    int* __restrict__ row_ptr,
                                                    int* __restrict__ col,
                                                    float* __restrict__ dis, int n) {
    __shared__ int c[128], fl[128], sc[128];
    int t = threadIdx.x, k = blockIdx.x;
    if (t < 128) c[t] = 0;
    __syncthreads();
    int beg = bb[k], end = bb[k + 1];
    for (int i = beg + t; i < end; i += 256) atomicAdd(&c[(ebuf[i] >> 17) & 127], 1);
    __syncthreads();
    if (t < 128) sc[t] = c[t];
    __syncthreads();
    for (int off = 1; off < 128; off <<= 1) {
        int x = (t >= off && t < 128) ? sc[t - off] : 0;
        __syncthreads();
        if (t < 128) sc[t] += x;
        __syncthreads();
    }
    if (t < 128) {
        int rb = beg + sc[t] - c[t];
        fl[t] = rb;
        int node = k * 128 + t;
        if (node < n) {
            row_ptr[node] = rb;
            dis[node] = rsqrtf((float)c[t] + 1.0f);
        }
    }
    __syncthreads();
    for (int i = beg + t; i < end; i += 256) {
        int e = ebuf[i];
        int pos = atomicAdd(&fl[(e >> 17) & 127], 1);
        col[pos] = e & 0x1FFFF;
    }
}

// ---------------- per-node prep: g1 = dis * x (fp16) ----------------
__global__ void prep_kernel(const float* __restrict__ x, const float* __restrict__ dis,
                            __half* __restrict__ g1, int n) {
    int i = blockIdx.x * blockDim.x + threadIdx.x;
    if (i < n) {
        float ds = dis[i];
        const float4* xr = (const float4*)(x + (size_t)i * 8);
        float4 x0 = xr[0], x1 = xr[1];
        __half2 h0 = __floats2half2_rn(ds * x0.x, ds * x0.y);
        __half2 h1 = __floats2half2_rn(ds * x0.z, ds * x0.w);
        __half2 h2 = __floats2half2_rn(ds * x1.x, ds * x1.y);
        __half2 h3 = __floats2half2_rn(ds * x1.z, ds * x1.w);
        uint2 v0, v1;
        v0.x = *(unsigned*)&h0; v0.y = *(unsigned*)&h1;
        v1.x = *(unsigned*)&h2; v1.y = *(unsigned*)&h3;
        uint2* o = (uint2*)(g1 + (size_t)i * 8);
        o[0] = v0; o[1] = v1;
    }
}

// ---------------- layer-1 pre-aggregation on 8-dim input ----------------
__global__ __launch_bounds__(256) void agg1_kernel(const __half* __restrict__ g1,
                                                   const int* __restrict__ row_ptr,
                                                   const int* __restrict__ col,
                                                   const float* __restrict__ dis,
                                                   float* __restrict__ p, int n) {
    int node = blockIdx.x * 4 + (threadIdx.x >> 6);
    if (node >= n) return;
    int lane = threadIdx.x & 63;
    int grp = lane >> 2;   // edge slot 0..15
    int fid = lane & 3;    // feature pair id
    int beg = row_ptr[node], end = row_ptr[node + 1];
    float a0 = 0.f, a1 = 0.f;
    for (int e0 = beg; e0 < end; e0 += 16) {
        int m = end - e0;
        if (grp < m) {
            int c = col[e0 + grp];
            __half2 h2 = *(const __half2*)(g1 + (size_t)c * 8 + fid * 2);
            float2 f = __half22float2(h2);
            a0 += f.x; a1 += f.y;
        }
    }
    a0 += __shfl_xor(a0, 4);  a1 += __shfl_xor(a1, 4);
    a0 += __shfl_xor(a0, 8);  a1 += __shfl_xor(a1, 8);
    a0 += __shfl_xor(a0, 16); a1 += __shfl_xor(a1, 16);
    a0 += __shfl_xor(a0, 32); a1 += __shfl_xor(a1, 32);
    if (lane < 4) {
        __half2 own = *(const __half2*)(g1 + (size_t)node * 8 + fid * 2);
        float2 fo = __half22float2(own);
        float d = dis[node];
        *(float2*)(p + (size_t)node * 8 + fid * 2) = make_float2(d * (a0 + fo.x), d * (a1 + fo.y));
    }
}

__device__ inline uint2 f4_to_h4(float4 v) {
    __half2 a = __floats2half2_rn(v.x, v.y);
    __half2 b = __floats2half2_rn(v.z, v.w);
    uint2 r;
    r.x = *(unsigned*)&a;
    r.y = *(unsigned*)&b;
    return r;
}

// ---------------- GEMM layer 1: p[N x 8] fp32 @ W[8 x 128] + b, relu -> fp16 -------
__global__ __launch_bounds__(256) void gemm_k8(const float* __restrict__ A,
                                               const float* __restrict__ W,
                                               const float* __restrict__ bias,
                                               __half* __restrict__ out, int n) {
    __shared__ float4 Ws[8 * 32];
    const float4* W4 = (const float4*)W;
    for (int i = threadIdx.x; i < 8 * 32; i += 256) Ws[i] = W4[i];
    __syncthreads();
    int r = blockIdx.x * 256 + threadIdx.x;
    if (r >= n) return;
    float4 acc[32];
    #pragma unroll
    for (int j = 0; j < 32; j++) acc[j] = make_float4(0.f, 0.f, 0.f, 0.f);
    const float4* Arow = (const float4*)(A + (size_t)r * 8);
    float4 a0 = Arow[0], a1 = Arow[1];
    float av[8] = {a0.x, a0.y, a0.z, a0.w, a1.x, a1.y, a1.z, a1.w};
    #pragma unroll
    for (int kk = 0; kk < 8; kk++) {
        float a = av[kk];
        #pragma unroll
        for (int j = 0; j < 32; j++) {
            float4 w = Ws[kk * 32 + j];
            acc[j].x += a * w.x;
            acc[j].y += a * w.y;
            acc[j].z += a * w.z;
            acc[j].w += a * w.w;
        }
    }
    uint2* o = (uint2*)(out + (size_t)r * HID);
    const float4* b4 = (const float4*)bias;
    #pragma unroll
    for (int j = 0; j < 32; j++) {
        float4 b = b4[j];
        float4 v = make_float4(fmaxf(acc[j].x + b.x, 0.f), fmaxf(acc[j].y + b.y, 0.f),
                               fmaxf(acc[j].z + b.z, 0.f), fmaxf(acc[j].w + b.w, 0.f));
        o[j] = f4_to_h4(v);
    }
}

// ---------------- W transpose+convert: Wt[j][k] = (fp16) W[k][j] ----------------
__global__ __launch_bounds__(128) void wconv(const float* __restrict__ W,
                                             __half* __restrict__ Wt) {
    int j = blockIdx.x, k = threadIdx.x;
    Wt[j * 128 + k] = __float2half(W[k * 128 + j]);
}

// ---------------- MFMA GEMM layers 2..5: gq = fp8(dis * (h @ W)) ----------------
__global__ __launch_bounds__(256) void gemm_mfma(const __half* __restrict__ A,
                                                 const __half* __restrict__ Wt,
                                                 const float* __restrict__ dis,
                                                 unsigned char* __restrict__ outq, int n) {
    __shared__ uint4 wt_lds[128 * 17];  // 17 uint4 = 136 halves per row
    __shared__ uint4 a_lds[64 * 17];
    int t = threadIdx.x;
    const uint4* Wg = (const uint4*)Wt;
    #pragma unroll
    for (int i = 0; i < 8; i++) {
        int idx = i * 256 + t;
        int j = idx >> 4, kq = idx & 15;
        wt_lds[j * 17 + kq] = Wg[idx];
    }
    int base = blockIdx.x * 64;
    const uint4* Ag = (const uint4*)A;
    #pragma unroll
    for (int i = 0; i < 4; i++) {
        int idx = i * 256 + t;
        int r = idx >> 4, kq = idx & 15;
        int row = base + r;
        if (row >= n) row = n - 1;
        a_lds[r * 17 + kq] = Ag[(size_t)row * 16 + kq];
    }
    __syncthreads();
    int w = t >> 6, lane = t & 63;
    int m = lane & 15, quad = lane >> 4;
    floatx4 acc[8];
    #pragma unroll
    for (int jt = 0; jt < 8; jt++) acc[jt] = (floatx4)(0.f);
    #pragma unroll
    for (int kc = 0; kc < 4; kc++) {
        uint4 araw = a_lds[(w * 16 + m) * 17 + kc * 4 + quad];
        half8 af = *(half8*)&araw;
        #pragma unroll
        for (int jt = 0; jt < 8; jt++) {
            uint4 braw = wt_lds[(jt * 16 + m) * 17 + kc * 4 + quad];
            half8 bf = *(half8*)&braw;
            acc[jt] = __builtin_amdgcn_mfma_f32_16x16x32_f16(af, bf, acc[jt], 0, 0, 0);
        }
    }
    #pragma unroll
    for (int reg = 0; reg < 4; reg++) {
        int row = base + w * 16 + quad * 4 + reg;
        if (row < n) {
            float ds = dis[row];
            #pragma unroll
            for (int jt = 0; jt < 8; jt++) {
                outq[(size_t)row * 128 + jt * 16 + m] = f32_to_fp8(acc[jt][reg] * ds);
            }
        }
    }
}

// ---------------- aggregation: h_next = relu(dis_d*(sum gq_src + gq_d) + b) ---------
// wave per node; 16 lanes x uint2 (8B fp8) per edge row -> 4 edges per gather instr.
// (R11's 8-lane x uint4 shape regressed 61->73us: wider accumulator set + 16
// line-requests/instr — keep this shape.)
__global__ __launch_bounds__(256) void agg_kernel(const unsigned char* __restrict__ gq,
                                                  const int* __restrict__ row_ptr,
                                                  const int* __restrict__ col,
                                                  const float* __restrict__ dis,
                                                  const float* __restrict__ bias,
                                                  __half* __restrict__ out, int n) {
    int node = blockIdx.x * 4 + (threadIdx.x >> 6);
    if (node >= n) return;
    int lane = threadIdx.x & 63;
    int grp = lane >> 4;        // edge slot within a 4-edge step
    int fl = (lane & 15) * 8;   // 8 features per lane
    int beg = row_ptr[node], end = row_ptr[node + 1];
    floatx2 a01 = {0.f, 0.f}, a23 = {0.f, 0.f}, a45 = {0.f, 0.f}, a67 = {0.f, 0.f};
    for (int e0 = beg; e0 < end; e0 += 64) {
        int m = min(64, end - e0);
        int cl = (lane < m) ? col[e0 + lane] : 0;
        int full = m >> 4;  // complete 16-edge steps (mask-free)
        for (int j = 0; j < full; j++) {
            int c[4];
            #pragma unroll
            for (int u = 0; u < 4; u++) c[u] = __shfl(cl, j * 16 + u * 4 + grp);
            uint2 raw[4];
            #pragma unroll
            for (int u = 0; u < 4; u++)
                raw[u] = *(const uint2*)(gq + (size_t)c[u] * 128 + fl);
            #pragma unroll
            for (int u = 0; u < 4; u++) {
                a01 += __builtin_amdgcn_cvt_pk_f32_fp8(raw[u].x, false);
                a23 += __builtin_amdgcn_cvt_pk_f32_fp8(raw[u].x, true);
                a45 += __builtin_amdgcn_cvt_pk_f32_fp8(raw[u].y, false);
                a67 += __builtin_amdgcn_cvt_pk_f32_fp8(raw[u].y, true);
            }
        }
        // partial tail (masked, 4 edges per pass)
        for (int j4 = full * 16; j4 < m; j4 += 4) {
            int idx = j4 + grp;
            int c = __shfl(cl, idx & 63);
            float val = (idx < m) ? 1.f : 0.f;
            uint2 raw = *(const uint2*)(gq + (size_t)c * 128 + fl);
            floatx2 f0 = __builtin_amdgcn_cvt_pk_f32_fp8(raw.x, false);
            floatx2 f1 = __builtin_amdgcn_cvt_pk_f32_fp8(raw.x, true);
            floatx2 f2 = __builtin_amdgcn_cvt_pk_f32_fp8(raw.y, false);
            floatx2 f3 = __builtin_amdgcn_cvt_pk_f32_fp8(raw.y, true);
            a01 += val * f0;
            a23 += val * f1;
            a45 += val * f2;
            a67 += val * f3;
        }
    }
    float a[8] = {a01[0], a01[1], a23[0], a23[1], a45[0], a45[1], a67[0], a67[1]};
    #pragma unroll
    for (int k = 0; k < 8; k++) {
        a[k] += __shfl_xor(a[k], 16);
        a[k] += __shfl_xor(a[k], 32);
    }
    if (lane < 16) {
        float d = dis[node];
        uint2 own = *(const uint2*)(gq + (size_t)node * 128 + fl);
        floatx2 s0 = __builtin_amdgcn_cvt_pk_f32_fp8(own.x, false);
        floatx2 s1 = __builtin_amdgcn_cvt_pk_f32_fp8(own.x, true);
        floatx2 s2 = __builtin_amdgcn_cvt_pk_f32_fp8(own.y, false);
        floatx2 s3 = __builtin_amdgcn_cvt_pk_f32_fp8(own.y, true);
        float sv[8] = {s0[0], s0[1], s1[0], s1[1], s2[0], s2[1], s3[0], s3[1]};
        float4 b0 = *(const float4*)(bias + fl);
        float4 b1 = *(const float4*)(bias + fl + 4);
        float bv[8] = {b0.x, b0.y, b0.z, b0.w, b1.x, b1.y, b1.z, b1.w};
        float o[8];
        #pragma unroll
        for (int k = 0; k < 8; k++) o[k] = fmaxf(d * (a[k] + sv[k]) + bv[k], 0.f);
        uint4 q;
        __half2 q0 = __floats2half2_rn(o[0], o[1]);
        __half2 q1 = __floats2half2_rn(o[2], o[3]);
        __half2 q2 = __floats2half2_rn(o[4], o[5]);
        __half2 q3 = __floats2half2_rn(o[6], o[7]);
        q.x = *(unsigned*)&q0;
        q.y = *(unsigned*)&q1;
        q.z = *(unsigned*)&q2;
        q.w = *(unsigned*)&q3;
        *(uint4*)(out + (size_t)node * HID + fl) = q;
    }
}

// ---------------- graph boundaries via binary search (batch is sorted) ---------
__global__ __launch_bounds__(128) void gbounds_kernel(const int* __restrict__ batch,
                                                      int* __restrict__ bnd,
                                                      int* __restrict__ gcnt) {
    int g = threadIdx.x;
    if (g <= N_GRAPHS) {
        int lo = 0, hi = N_NODES;
        while (lo < hi) {
            int mid = (lo + hi) >> 1;
            if (batch[mid] < g) lo = mid + 1;
            else hi = mid;
        }
        bnd[g] = lo;
    }
    __syncthreads();
    if (g < N_GRAPHS) gcnt[g] = bnd[g + 1] - bnd[g];
}

__global__ __launch_bounds__(128) void pool_kernel(const __half* __restrict__ h,
                                                   const int* __restrict__ batch,
                                                   float* __restrict__ pooled, int n) {
    int f = threadIdx.x;
    int n0 = blockIdx.x * 64;
    if (n0 >= n) return;
    int n1 = min(n0 + 64, n);
    float acc = 0.f;
    int cur = batch[n0];
    for (int i = n0; i < n1; i++) {
        int b = batch[i];
        if (b != cur) {
            atomicAdd(&pooled[cur * HID + f], acc);
            acc = 0.f;
            cur = b;
        }
        acc += __half2float(h[(size_t)i * HID + f]);
    }
    atomicAdd(&pooled[cur * HID + f], acc);
}

// ---------------- head: mean, dense 128->10, log_softmax ----------------
__global__ __launch_bounds__(128) void final_kernel(const float* __restrict__ pooled,
                                                    const int* __restrict__ gcnt,
                                                    const float* __restrict__ Wout,
                                                    const float* __restrict__ bout,
                                                    float* __restrict__ out) {
    __shared__ float p[HID];
    __shared__ float lg[10];
    __shared__ float lsum;
    int g = blockIdx.x, t = threadIdx.x;
    float c = fmaxf((float)gcnt[g], 1.0f);
    p[t] = pooled[g * HID + t] / c;
    __syncthreads();
    if (t < 10) {
        float s = bout[t];
        for (int f = 0; f < HID; f++) s += p[f] * Wout[f * 10 + t];
        lg[t] = s;
    }
    __syncthreads();
    if (t == 0) {
        float m = lg[0];
        for (int ci = 1; ci < 10; ci++) m = fmaxf(m, lg[ci]);
        float se = 0.f;
        for (int ci = 0; ci < 10; ci++) se += expf(lg[ci] - m);
        lsum = m + logf(se);
    }
    __syncthreads();
    if (t < 10) out[g * 10 + t] = lg[t] - lsum;
}

extern "C" void kernel_launch(void* const* d_in, const int* in_sizes, int n_in,
                              void* d_out, int out_size, void* d_ws, size_t ws_size,
                              hipStream_t stream) {
    const float* x = (const float*)d_in[0];
    const int* ei = (const int*)d_in[1];
    const int* batch = (const int*)d_in[2];
    const float* W[5] = {(const float*)d_in[3], (const float*)d_in[5], (const float*)d_in[7],
                         (const float*)d_in[9], (const float*)d_in[11]};
    const float* B[5] = {(const float*)d_in[4], (const float*)d_in[6], (const float*)d_in[8],
                         (const float*)d_in[10], (const float*)d_in[12]};
    const float* Wout = (const float*)d_in[13];
    const float* bout = (const float*)d_in[14];
    float* out = (float*)d_out;

    const int* src = ei;
    const int* dst = ei + N_EDGES;

    char* ws = (char*)d_ws;
    size_t off = 0;
    auto alloc = [&](size_t bytes) -> char* {
        char* p = ws + off;
        off = (off + bytes + 255) & ~(size_t)255;
        return p;
    };
    float* pooled = (float*)alloc(N_GRAPHS * HID * 4);
    size_t zero_span = off;  // pooled gets memset to 0
    int* gcnt = (int*)alloc(N_GRAPHS * 4);
    int* bnd = (int*)alloc((N_GRAPHS + 1) * 4);
    int* row_ptr = (int*)alloc((N_NODES + 1) * 4);
    float* dis = (float*)alloc(N_NODES * 4);
    int* hist_g = (int*)alloc((size_t)NBUCK * NPART * 4);
    int* tot = (int*)alloc(NBUCK * 4);
    int* bb = (int*)alloc((NBUCK + 1) * 4);
    int* ebuf = (int*)alloc((size_t)N_EDGES * 4);
    int* col = (int*)alloc((size_t)N_EDGES * 4);
    __half* wt = (__half*)alloc(4 * 128 * 128 * 2);
    __half* g1 = (__half*)alloc((size_t)N_NODES * 8 * 2);
    float* p1 = (float*)alloc((size_t)N_NODES * 8 * 4);
    __half* h_a = (__half*)alloc((size_t)N_NODES * HID * 2);
    unsigned char* gq = (unsigned char*)alloc((size_t)N_NODES * HID);

    hipMemsetAsync(d_ws, 0, zero_span, stream);

    int nb = (N_NODES + 255) / 256;
    int wb = (NBUCK + 3) / 4;  // 196 blocks, 4 waves each

    // CSR build: counting sort, zero device-scope atomics, parallel scan
    hist_kernel<<<NPART, 256, 0, stream>>>(dst, hist_g);
    tot_kernel<<<wb, 256, 0, stream>>>(hist_g, tot);
    scan_tot<<<1, 1024, 0, stream>>>(tot, bb, row_ptr + N_NODES);
    offs_kernel<<<wb, 256, 0, stream>>>(hist_g, bb);
    part_kernel<<<NPART, 256, 0, stream>>>(src, dst, hist_g, ebuf);
    build_kernel<<<NBUCK, 256, 0, stream>>>(ebuf, bb, row_ptr, col, dis, N_NODES);

    prep_kernel<<<nb, 256, 0, stream>>>(x, dis, g1, N_NODES);
    gbounds_kernel<<<1, 128, 0, stream>>>(batch, bnd, gcnt);
    for (int l = 1; l < 5; l++)
        wconv<<<128, 128, 0, stream>>>(W[l], wt + (size_t)(l - 1) * 128 * 128);

    int gb = (N_NODES + 255) / 256;
    int ab = (N_NODES + 3) / 4;
    int mb = (N_NODES + 63) / 64;

    // layer 1: agg on 8-dim input, then GEMM 8->128 (+bias, relu)
    agg1_kernel<<<ab, 256, 0, stream>>>(g1, row_ptr, col, dis, p1, N_NODES);
    gemm_k8<<<gb, 256, 0, stream>>>(p1, W[0], B[0], h_a, N_NODES);
    // layers 2..5: MFMA GEMM (gq = fp8(dis*hW)) then agg (+bias, relu)
    for (int l = 1; l < 5; l++) {
        gemm_mfma<<<mb, 256, 0, stream>>>(h_a, wt + (size_t)(l - 1) * 128 * 128, dis, gq,
                                          N_NODES);
        agg_kernel<<<ab, 256, 0, stream>>>(gq, row_ptr, col, dis, B[l], h_a, N_NODES);
    }

    pool_kernel<<<(N_NODES + 63) / 64, 128, 0, stream>>>(h_a, batch, pooled, N_NODES);
    final_kernel<<<N_GRAPHS, 128, 0, stream>>>(pooled, gcnt, Wout, bout, out);
}